// Round 10
// baseline (126.379 us; speedup 1.0000x reference)
//
#include <hip/hip_runtime.h>

// CoAttention, 3-kernel pipeline. R10:
//  k_proj : merged into 2 mega-GEMMs 1024x768 (A=ctx1: [Wh1|W12b|W21a],
//           A=ctx2: [Wh2|W12a|W21b]); tile 64x96 -> grid 256 = 1 block/CU
//           (was 384 = 1.5/CU stragglers), A staged once per 96 cols.
//  k_aff  : pairwise-rcp identity w1/x1+w2/x2 = (w1x2+w2x1)*rcp(x1x2):
//           halves trans ops (6.8->3.4us); w via uniform scalar loads
//           (LDS reads 7->6 b128 per 4k); -2 folded into final exp.
//  k_final: unchanged (bf16 MFMA, R9).

#define NEGC (-1e12f)
#define TWO_LOG2E 2.8853900817779268f
#define LOG2E 1.4426950408889634f
#define N2LOG2E (-2.8853900817779268f)

typedef __attribute__((ext_vector_type(8))) short bf16x8;
typedef __attribute__((ext_vector_type(4))) float f32x4;

__device__ __forceinline__ short f2bf(float x)   // RNE f32->bf16
{
    union { float f; unsigned u; } v; v.f = x;
    unsigned r = (v.u + 0x7FFFu + ((v.u >> 16) & 1u)) >> 16;
    return (short)r;
}

// ---------------------------------------------------------------- k_proj
// z=0: ctx1 @ [Wh1 | W12b | W21a] -> [E1 | U1 | P21]
// z=1: ctx2 @ [Wh2 | W12a | W21b] -> [E2 | P12 | U2]
__global__ __launch_bounds__(256) void k_proj(
    const float* __restrict__ ctx1, const float* __restrict__ ctx2,
    const float* __restrict__ Wh, const float* __restrict__ bh,
    const float* __restrict__ W12, const float* __restrict__ b12,
    const float* __restrict__ W21, const float* __restrict__ b21,
    const float* __restrict__ mask1, const float* __restrict__ mask2,
    float* __restrict__ E1, float* __restrict__ E2,
    float* __restrict__ P12, float* __restrict__ U1,
    float* __restrict__ P21, float* __restrict__ U2,
    float* __restrict__ p1, float* __restrict__ p2,
    float* __restrict__ S1, float* __restrict__ S2)
{
    const int t  = threadIdx.x;
    const int z  = blockIdx.z;
    const int r0 = blockIdx.x * 64;       // rows = l*2+b in [0,1024)
    const int n0 = blockIdx.y * 96;       // mega-col in [0,768)

    const float* A = z ? ctx2 : ctx1;

    if (z == 0 && blockIdx.x == 0 && blockIdx.y == 0) {
        for (int idx = t; idx < 1024; idx += 256) {
            int row = idx >> 1, b = idx & 1;
            p1[b * 512 + row] = __builtin_amdgcn_exp2f(LOG2E * (1.f - mask1[idx]) * NEGC);
            p2[b * 512 + row] = __builtin_amdgcn_exp2f(LOG2E * (1.f - mask2[idx]) * NEGC);
            S1[b * 512 + row] = 0.f;
            S2[b * 512 + row] = 0.f;
        }
    }

    __shared__ __align__(16) short Abf[64 * 136];   // [m][k] bf16
    __shared__ __align__(16) short Bbf[96 * 136];   // [n][k] bf16 (W^T)

    const int w    = t >> 6;
    const int lane = t & 63;
    const int quad = lane >> 4;
    const int lr   = lane & 15;

    f32x4 acc[6] = {};                    // 6 n-chunks of 16

    for (int kc = 0; kc < 256; kc += 128) {
        #pragma unroll
        for (int i = 0; i < 8; ++i) {                 // A: 64 rows x 128 k
            int slot = i * 256 + t;
            int r = slot >> 5, kq = (slot & 31) << 2;
            float4 v = *(const float4*)(A + (r0 + r) * 256 + kc + kq);
            short4 s; s.x = f2bf(v.x); s.y = f2bf(v.y); s.z = f2bf(v.z); s.w = f2bf(v.w);
            *(short4*)(Abf + r * 136 + kq) = s;
        }
        #pragma unroll
        for (int i = 0; i < 12; ++i) {                // B: 128 k x 96 n -> B^T
            int slot = i * 256 + t;                   // 0..3071
            int bk = slot / 24;                       // 0..127
            int bn4 = (slot - bk * 24) << 2;          // 0..92
            int ncol = n0 + bn4;
            int gsel = ncol >> 8;
            int c = ncol & 255;
            const float* Wp; int rbase;
            if (gsel == 0)      { Wp = Wh;  rbase = z ? 256 : 0; }
            else if (gsel == 1) { Wp = W12; rbase = z ? 0 : 256; }
            else                { Wp = W21; rbase = z ? 256 : 0; }
            float4 v = *(const float4*)(Wp + (rbase + kc + bk) * 256 + c);
            Bbf[(bn4 + 0) * 136 + bk] = f2bf(v.x);
            Bbf[(bn4 + 1) * 136 + bk] = f2bf(v.y);
            Bbf[(bn4 + 2) * 136 + bk] = f2bf(v.z);
            Bbf[(bn4 + 3) * 136 + bk] = f2bf(v.w);
        }
        __syncthreads();
        #pragma unroll
        for (int s = 0; s < 4; ++s) {
            const int kb = s * 32 + quad * 8;
            bf16x8 a = *(const bf16x8*)(Abf + (w * 16 + lr) * 136 + kb);
            #pragma unroll
            for (int nc = 0; nc < 6; ++nc) {
                bf16x8 b = *(const bf16x8*)(Bbf + (nc * 16 + lr) * 136 + kb);
                acc[nc] = __builtin_amdgcn_mfma_f32_16x16x32_bf16(a, b, acc[nc], 0, 0, 0);
            }
        }
        __syncthreads();
    }

    #pragma unroll
    for (int nc = 0; nc < 6; ++nc) {
        const int ncb  = n0 + nc * 16;                // 16-col subtile, never
        const int gsel = ncb >> 8;                    // straddles a 256-boundary
        const int col  = (ncb & 255) + lr;
        float* outp; const float* bias; int expm;
        if (z == 0) {
            if (gsel == 0)      { outp = E1;  bias = bh;      expm = 1; }
            else if (gsel == 1) { outp = U1;  bias = nullptr; expm = 0; }
            else                { outp = P21; bias = b21;     expm = 0; }
        } else {
            if (gsel == 0)      { outp = E2;  bias = nullptr; expm = 1; }
            else if (gsel == 1) { outp = P12; bias = b12;     expm = 0; }
            else                { outp = U2;  bias = nullptr; expm = 0; }
        }
        const float bv = bias ? bias[col] : 0.f;
        #pragma unroll
        for (int reg = 0; reg < 4; ++reg) {
            int row  = r0 + w * 16 + quad * 4 + reg;   // = l*2+b
            int orow = ((row & 1) << 9) + (row >> 1);
            float v = acc[nc][reg] + bv;
            if (expm) v = __builtin_amdgcn_exp2f(v * TWO_LOG2E);
            outp[orow * 256 + col] = v;
        }
    }
}

// ---------------------------------------------------------------- k_aff
// PAIR: acc += w.x/x0 + w.y/x1 + w.z/x2 + w.w/x3 with 2 rcp via pairing.
#define PAIR(AV, QV, WV, ACC) do {                                    \
    float x0_ = fmaf(AV.x, QV.x, 1.f);                                \
    float x1_ = fmaf(AV.y, QV.y, 1.f);                                \
    float x2_ = fmaf(AV.z, QV.z, 1.f);                                \
    float x3_ = fmaf(AV.w, QV.w, 1.f);                                \
    float r01_ = __builtin_amdgcn_rcpf(x0_ * x1_);                    \
    float r23_ = __builtin_amdgcn_rcpf(x2_ * x3_);                    \
    float z01_ = fmaf(WV.y, x0_, WV.x * x1_);                         \
    float z23_ = fmaf(WV.w, x2_, WV.z * x3_);                         \
    ACC = fmaf(r01_, z01_, ACC);                                      \
    ACC = fmaf(r23_, z23_, ACC);                                      \
} while (0)

__global__ __launch_bounds__(256) void k_aff(
    const float* __restrict__ E1g, const float* __restrict__ E2g,
    const float* __restrict__ wo,
    const float* __restrict__ p1g, const float* __restrict__ p2g,
    float* __restrict__ EN, float* __restrict__ ET,
    float* __restrict__ S1, float* __restrict__ S2)
{
    const int t  = threadIdx.x;
    const int l0 = blockIdx.x * 64, m0 = blockIdx.y * 32, b = blockIdx.z;

    __shared__ __align__(16) float E1s[64 * 132];
    __shared__ __align__(16) float E2s[32 * 132];
    __shared__ __align__(16) float affs[64 * 36];

    const int tl = t >> 4, tm = t & 15;   // cells: l = tl+16i (i<4), m = tm, tm+16
    float acc[4][2] = {};

    for (int kc = 0; kc < 256; kc += 128) {
        #pragma unroll
        for (int i = 0; i < 8; ++i) {
            int slot = i * 256 + t;
            int r = slot >> 5, kq = (slot & 31) << 2;
            *(float4*)(E1s + r * 132 + kq) =
                *(const float4*)(E1g + (((b << 9) + l0 + r) << 8) + kc + kq);
        }
        #pragma unroll
        for (int i = 0; i < 4; ++i) {
            int slot = i * 256 + t;
            int r = slot >> 5, kq = (slot & 31) << 2;
            *(float4*)(E2s + r * 132 + kq) =
                *(const float4*)(E2g + (((b << 9) + m0 + r) << 8) + kc + kq);
        }
        __syncthreads();
        #pragma unroll 4
        for (int k0 = 0; k0 < 128; k0 += 4) {
            const float4 w  = *(const float4*)(wo + kc + k0);   // uniform -> s_load
            const float4 q0 = *(const float4*)(E2s + tm * 132 + k0);
            const float4 q1 = *(const float4*)(E2s + (tm + 16) * 132 + k0);
            #pragma unroll
            for (int i = 0; i < 4; ++i) {
                const float4 a = *(const float4*)(E1s + (tl + 16 * i) * 132 + k0);
                PAIR(a, q0, w, acc[i][0]);
                PAIR(a, q1, w, acc[i][1]);
            }
        }
        __syncthreads();
    }

    // aff = -2*acc (the -2*wo factor folded here); E = exp(aff), SW cancels
    #pragma unroll
    for (int i = 0; i < 4; ++i) {
        affs[(tl + 16 * i) * 36 + tm]      = __builtin_amdgcn_exp2f(acc[i][0] * N2LOG2E);
        affs[(tl + 16 * i) * 36 + tm + 16] = __builtin_amdgcn_exp2f(acc[i][1] * N2LOG2E);
    }
    __syncthreads();

    // natural pass (64 l-rows x 32 m-cols): EN[l][m]=E*p1[l]; S1[l]+=sum_m E*p2[m]
    #pragma unroll
    for (int i = 0; i < 2; ++i) {
        int slot = i * 256 + t;
        int r = slot >> 3, c4 = (slot & 7) << 2;
        float4 e   = *(const float4*)(affs + r * 36 + c4);
        const float p1r = p1g[(b << 9) + l0 + r];
        float4 vn = make_float4(e.x * p1r, e.y * p1r, e.z * p1r, e.w * p1r);
        *(float4*)(EN + (((b << 9) + l0 + r) << 9) + m0 + c4) = vn;
        float4 p2v = *(const float4*)(p2g + (b << 9) + m0 + c4);
        float s = (e.x * p2v.x + e.y * p2v.y) + (e.z * p2v.z + e.w * p2v.w);
        s += __shfl_xor(s, 1, 64);
        s += __shfl_xor(s, 2, 64);
        s += __shfl_xor(s, 4, 64);
        if ((t & 7) == 0) atomicAdd(S1 + (b << 9) + l0 + r, s);
    }
    // transposed pass (32 m-rows x 64 l-cols): ET[m][l]=E^T*p2[m]; S2[m]+=sum_l E*p1[l]
    #pragma unroll
    for (int i = 0; i < 2; ++i) {
        int slot = i * 256 + t;
        int r = slot >> 4, c4 = (slot & 15) << 2;
        float4 te;
        te.x = affs[(c4 + 0) * 36 + r];
        te.y = affs[(c4 + 1) * 36 + r];
        te.z = affs[(c4 + 2) * 36 + r];
        te.w = affs[(c4 + 3) * 36 + r];
        const float p2r = p2g[(b << 9) + m0 + r];
        float4 vt = make_float4(te.x * p2r, te.y * p2r, te.z * p2r, te.w * p2r);
        *(float4*)(ET + (((b << 9) + m0 + r) << 9) + l0 + c4) = vt;
        float4 p1v = *(const float4*)(p1g + (b << 9) + l0 + c4);
        float s = (te.x * p1v.x + te.y * p1v.y) + (te.z * p1v.z + te.w * p1v.w);
        s += __shfl_xor(s, 1, 64);
        s += __shfl_xor(s, 2, 64);
        s += __shfl_xor(s, 4, 64);
        s += __shfl_xor(s, 8, 64);
        if ((t & 15) == 0) atomicAdd(S2 + (b << 9) + m0 + r, s);
    }
}

// --------------------------------------------------------------- k_final
__global__ __launch_bounds__(256) void k_final(
    const float* __restrict__ EN, const float* __restrict__ ET,
    const float* __restrict__ U1, const float* __restrict__ U2,
    const float* __restrict__ P12, const float* __restrict__ P21,
    const float* __restrict__ S1, const float* __restrict__ S2,
    float* __restrict__ out)
{
    const int t   = threadIdx.x;
    const int r0  = blockIdx.x * 32, n0 = blockIdx.y * 32;
    const int dir = blockIdx.z >> 1, b = blockIdx.z & 1;
    const float* Ag = (dir == 0 ? ET  : EN)  + b * 262144;  // [row][k], stride 512
    const float* Sg = (dir == 0 ? S1  : S2)  + b * 512;
    const float* Bg = (dir == 0 ? U1  : U2)  + b * 131072;  // [k][n], stride 256
    const float* Pg = (dir == 0 ? P12 : P21) + b * 131072;  // [row][n], stride 256
    float* o = out + (dir == 0 ? 262144 : 0);

    __shared__ __align__(16) short Abf[32 * 72];    // [row][k] bf16, rs folded
    __shared__ __align__(16) short Bbf[32 * 72];    // [n][k] bf16 (U^T)
    __shared__ __align__(16) float rs[512];

    for (int i = t; i < 512; i += 256)
        rs[i] = __builtin_amdgcn_rcpf(Sg[i]);
    __syncthreads();

    const int w    = t >> 6;
    const int lane = t & 63;
    const int quad = lane >> 4;
    const int lr   = lane & 15;
    const int wr   = (w >> 1) << 4, wc = (w & 1) << 4;
    f32x4 acc = {};

    for (int kc = 0; kc < 512; kc += 64) {
        #pragma unroll
        for (int i = 0; i < 2; ++i) {               // A: 32 rows x 64 k, rs-scaled
            int slot = i * 256 + t;
            int r = slot >> 4, kq = (slot & 15) << 2;
            float4 v = *(const float4*)(Ag + ((r0 + r) << 9) + kc + kq);
            const float* rp = rs + kc + kq;
            short4 s;
            s.x = f2bf(v.x * rp[0]); s.y = f2bf(v.y * rp[1]);
            s.z = f2bf(v.z * rp[2]); s.w = f2bf(v.w * rp[3]);
            *(short4*)(Abf + r * 72 + kq) = s;
        }
        #pragma unroll
        for (int i = 0; i < 2; ++i) {               // B: 64 k x 32 n -> [n][k]
            int slot = i * 256 + t;
            int bk = slot >> 3, bn4 = (slot & 7) << 2;
            float4 v = *(const float4*)(Bg + ((kc + bk) << 8) + n0 + bn4);
            Bbf[(bn4 + 0) * 72 + bk] = f2bf(v.x);
            Bbf[(bn4 + 1) * 72 + bk] = f2bf(v.y);
            Bbf[(bn4 + 2) * 72 + bk] = f2bf(v.z);
            Bbf[(bn4 + 3) * 72 + bk] = f2bf(v.w);
        }
        __syncthreads();
        #pragma unroll
        for (int s = 0; s < 2; ++s) {
            const int kb = s * 32 + quad * 8;
            bf16x8 a = *(const bf16x8*)(Abf + (wr + lr) * 72 + kb);
            bf16x8 bb = *(const bf16x8*)(Bbf + (wc + lr) * 72 + kb);
            acc = __builtin_amdgcn_mfma_f32_16x16x32_bf16(a, bb, acc, 0, 0, 0);
        }
        __syncthreads();
    }

    const int col = n0 + wc + lr;
    #pragma unroll
    for (int reg = 0; reg < 4; ++reg) {
        const int m = r0 + wr + quad * 4 + reg;
        float v = acc[reg] + Pg[(m << 8) + col];
        float tv = 1.f - 2.f * __builtin_amdgcn_rcpf(
                       __builtin_amdgcn_exp2f(v * TWO_LOG2E) + 1.f);
        o[((m << 1) + b) * 256 + col] = tv;
    }
}

// ---------------------------------------------------------------- launch
extern "C" void kernel_launch(void* const* d_in, const int* in_sizes, int n_in,
                              void* d_out, int out_size, void* d_ws, size_t ws_size,
                              hipStream_t stream)
{
    const float* ctx1 = (const float*)d_in[0];
    const float* ctx2 = (const float*)d_in[1];
    const float* m1   = (const float*)d_in[2];
    const float* m2   = (const float*)d_in[3];
    const float* Wh   = (const float*)d_in[4];
    const float* bh   = (const float*)d_in[5];
    const float* wo   = (const float*)d_in[6];
    const float* W12  = (const float*)d_in[7];
    const float* b12  = (const float*)d_in[8];
    const float* W21  = (const float*)d_in[9];
    const float* b21  = (const float*)d_in[10];
    float* out = (float*)d_out;
    float* ws  = (float*)d_ws;

    float* E1  = ws;                 // 262144
    float* E2  = E1  + 262144;
    float* P12 = E2  + 262144;
    float* U1  = P12 + 262144;
    float* P21 = U1  + 262144;
    float* U2  = P21 + 262144;
    float* p1  = U2  + 262144;       // 1024
    float* p2  = p1  + 1024;
    float* S1  = p2  + 1024;         // 1024
    float* S2  = S1  + 1024;
    float* EN  = S2  + 1024;         // 524288
    float* ET  = EN  + 524288;       // 524288

    hipLaunchKernelGGL(k_proj, dim3(16, 8, 2), dim3(256), 0, stream,
                       ctx1, ctx2, Wh, bh, W12, b12, W21, b21, m1, m2,
                       E1, E2, P12, U1, P21, U2, p1, p2, S1, S2);
    hipLaunchKernelGGL(k_aff, dim3(8, 16, 2), dim3(256), 0, stream,
                       E1, E2, wo, p1, p2, EN, ET, S1, S2);
    hipLaunchKernelGGL(k_final, dim3(16, 8, 4), dim3(256), 0, stream,
                       EN, ET, U1, U2, P12, P21, S1, S2, out);
}

// Round 11
// 118.777 us; speedup vs baseline: 1.0640x; 1.0640x over previous
//
#include <hip/hip_runtime.h>

// CoAttention, 3-kernel pipeline. R11:
//  k_proj : reverted to R9 (3 GEMMs/ctx, grid 384; R10's 96-wide merge cost
//           occupancy + branchy staging -> +5.5us regression).
//  k_aff  : PAIR kept (2 rcp per 4 k's); tiles 64x32 -> 32x32, grid 512 =
//           2 blocks/CU (was 1) to hide rcp latency + LDS port time.
//  k_final: unchanged (bf16 MFMA).

#define NEGC (-1e12f)
#define TWO_LOG2E 2.8853900817779268f
#define LOG2E 1.4426950408889634f
#define N2LOG2E (-2.8853900817779268f)

typedef __attribute__((ext_vector_type(8))) short bf16x8;
typedef __attribute__((ext_vector_type(4))) float f32x4;

__device__ __forceinline__ short f2bf(float x)   // RNE f32->bf16
{
    union { float f; unsigned u; } v; v.f = x;
    unsigned r = (v.u + 0x7FFFu + ((v.u >> 16) & 1u)) >> 16;
    return (short)r;
}

// ---------------------------------------------------------------- k_proj
__global__ __launch_bounds__(256) void k_proj(
    const float* __restrict__ ctx1, const float* __restrict__ ctx2,
    const float* __restrict__ Wh, const float* __restrict__ bh,
    const float* __restrict__ W12, const float* __restrict__ b12,
    const float* __restrict__ W21, const float* __restrict__ b21,
    const float* __restrict__ mask1, const float* __restrict__ mask2,
    float* __restrict__ E1, float* __restrict__ E2,
    float* __restrict__ P12, float* __restrict__ U1,
    float* __restrict__ P21, float* __restrict__ U2,
    float* __restrict__ p1, float* __restrict__ p2,
    float* __restrict__ S1, float* __restrict__ S2)
{
    const int t  = threadIdx.x;
    const int g  = blockIdx.z;
    const int r0 = blockIdx.x * 64;       // rows = l*2+b in [0,1024)
    const int n0 = blockIdx.y * 64;       // N in [0,256)

    const float* A; const float* W; const float* bias; int expm; float* outp;
    switch (g) {
      case 0:  A=ctx1; W=Wh;        bias=bh;   expm=1; outp=E1;  break;
      case 1:  A=ctx2; W=Wh+65536;  bias=0;    expm=1; outp=E2;  break;
      case 2:  A=ctx2; W=W12;       bias=b12;  expm=0; outp=P12; break;
      case 3:  A=ctx1; W=W12+65536; bias=0;    expm=0; outp=U1;  break;
      case 4:  A=ctx1; W=W21;       bias=b21;  expm=0; outp=P21; break;
      default: A=ctx2; W=W21+65536; bias=0;    expm=0; outp=U2;  break;
    }

    if (g == 0 && blockIdx.x == 0 && blockIdx.y == 0) {
        for (int idx = t; idx < 1024; idx += 256) {
            int row = idx >> 1, b = idx & 1;
            p1[b * 512 + row] = __builtin_amdgcn_exp2f(LOG2E * (1.f - mask1[idx]) * NEGC);
            p2[b * 512 + row] = __builtin_amdgcn_exp2f(LOG2E * (1.f - mask2[idx]) * NEGC);
            S1[b * 512 + row] = 0.f;
            S2[b * 512 + row] = 0.f;
        }
    }

    __shared__ __align__(16) short Abf[64 * 136];   // [m][k] bf16
    __shared__ __align__(16) short Bbf[64 * 136];   // [n][k] bf16 (W^T)

    const int w    = t >> 6;
    const int lane = t & 63;
    const int quad = lane >> 4;
    const int lr   = lane & 15;

    f32x4 acc[4] = {};

    for (int kc = 0; kc < 256; kc += 128) {
        #pragma unroll
        for (int i = 0; i < 8; ++i) {                 // A: 64 rows x 128 k
            int slot = i * 256 + t;
            int r = slot >> 5, kq = (slot & 31) << 2;
            float4 v = *(const float4*)(A + (r0 + r) * 256 + kc + kq);
            short4 s; s.x = f2bf(v.x); s.y = f2bf(v.y); s.z = f2bf(v.z); s.w = f2bf(v.w);
            *(short4*)(Abf + r * 136 + kq) = s;
        }
        #pragma unroll
        for (int i = 0; i < 8; ++i) {                 // B: 128 k x 64 n -> B^T
            int slot = i * 256 + t;
            int bk = slot >> 4, bn4 = (slot & 15) << 2;
            float4 v = *(const float4*)(W + (kc + bk) * 256 + n0 + bn4);
            Bbf[(bn4 + 0) * 136 + bk] = f2bf(v.x);
            Bbf[(bn4 + 1) * 136 + bk] = f2bf(v.y);
            Bbf[(bn4 + 2) * 136 + bk] = f2bf(v.z);
            Bbf[(bn4 + 3) * 136 + bk] = f2bf(v.w);
        }
        __syncthreads();
        #pragma unroll
        for (int s = 0; s < 4; ++s) {
            const int kb = s * 32 + quad * 8;
            bf16x8 a = *(const bf16x8*)(Abf + (w * 16 + lr) * 136 + kb);
            #pragma unroll
            for (int nc = 0; nc < 4; ++nc) {
                bf16x8 b = *(const bf16x8*)(Bbf + (nc * 16 + lr) * 136 + kb);
                acc[nc] = __builtin_amdgcn_mfma_f32_16x16x32_bf16(a, b, acc[nc], 0, 0, 0);
            }
        }
        __syncthreads();
    }

    #pragma unroll
    for (int nc = 0; nc < 4; ++nc) {
        const int col = n0 + nc * 16 + lr;
        const float bv = bias ? bias[col] : 0.f;
        #pragma unroll
        for (int reg = 0; reg < 4; ++reg) {
            int row  = r0 + w * 16 + quad * 4 + reg;   // = l*2+b
            int orow = ((row & 1) << 9) + (row >> 1);
            float v = acc[nc][reg] + bv;
            if (expm) v = __builtin_amdgcn_exp2f(v * TWO_LOG2E);
            outp[orow * 256 + col] = v;
        }
    }
}

// ---------------------------------------------------------------- k_aff
// PAIR: acc += w.x/x0 + w.y/x1 + w.z/x2 + w.w/x3 with 2 rcp via pairing.
#define PAIR(AV, QV, WV, ACC) do {                                    \
    float x0_ = fmaf(AV.x, QV.x, 1.f);                                \
    float x1_ = fmaf(AV.y, QV.y, 1.f);                                \
    float x2_ = fmaf(AV.z, QV.z, 1.f);                                \
    float x3_ = fmaf(AV.w, QV.w, 1.f);                                \
    float r01_ = __builtin_amdgcn_rcpf(x0_ * x1_);                    \
    float r23_ = __builtin_amdgcn_rcpf(x2_ * x3_);                    \
    float z01_ = fmaf(WV.y, x0_, WV.x * x1_);                         \
    float z23_ = fmaf(WV.w, x2_, WV.z * x3_);                         \
    ACC = fmaf(r01_, z01_, ACC);                                      \
    ACC = fmaf(r23_, z23_, ACC);                                      \
} while (0)

__global__ __launch_bounds__(256) void k_aff(
    const float* __restrict__ E1g, const float* __restrict__ E2g,
    const float* __restrict__ wo,
    const float* __restrict__ p1g, const float* __restrict__ p2g,
    float* __restrict__ EN, float* __restrict__ ET,
    float* __restrict__ S1, float* __restrict__ S2)
{
    const int t  = threadIdx.x;
    const int l0 = blockIdx.x * 32, m0 = blockIdx.y * 32, b = blockIdx.z;

    __shared__ __align__(16) float E1s[32 * 132];   // 16.9 KB
    __shared__ __align__(16) float E2s[32 * 132];   // 16.9 KB
    __shared__ __align__(16) float affs[32 * 36];   //  4.6 KB

    const int tl = t >> 4, tm = t & 15;   // cells: l in {tl,tl+16}, m in {tm,tm+16}
    float acc[2][2] = {};

    for (int kc = 0; kc < 256; kc += 128) {
        #pragma unroll
        for (int i = 0; i < 4; ++i) {               // 32 rows x 128 k, both panels
            int slot = i * 256 + t;
            int r = slot >> 5, kq = (slot & 31) << 2;
            *(float4*)(E1s + r * 132 + kq) =
                *(const float4*)(E1g + (((b << 9) + l0 + r) << 8) + kc + kq);
            *(float4*)(E2s + r * 132 + kq) =
                *(const float4*)(E2g + (((b << 9) + m0 + r) << 8) + kc + kq);
        }
        __syncthreads();
        #pragma unroll 4
        for (int k0 = 0; k0 < 128; k0 += 4) {
            const float4 w  = *(const float4*)(wo + kc + k0);   // uniform -> s_load
            const float4 a0 = *(const float4*)(E1s + tl * 132 + k0);
            const float4 a1 = *(const float4*)(E1s + (tl + 16) * 132 + k0);
            const float4 q0 = *(const float4*)(E2s + tm * 132 + k0);
            const float4 q1 = *(const float4*)(E2s + (tm + 16) * 132 + k0);
            PAIR(a0, q0, w, acc[0][0]);
            PAIR(a0, q1, w, acc[0][1]);
            PAIR(a1, q0, w, acc[1][0]);
            PAIR(a1, q1, w, acc[1][1]);
        }
        __syncthreads();
    }

    // aff = -2*acc (the -2*wo factor folded here); E = exp(aff), SW cancels
    affs[tl * 36 + tm]             = __builtin_amdgcn_exp2f(acc[0][0] * N2LOG2E);
    affs[tl * 36 + tm + 16]        = __builtin_amdgcn_exp2f(acc[0][1] * N2LOG2E);
    affs[(tl + 16) * 36 + tm]      = __builtin_amdgcn_exp2f(acc[1][0] * N2LOG2E);
    affs[(tl + 16) * 36 + tm + 16] = __builtin_amdgcn_exp2f(acc[1][1] * N2LOG2E);
    __syncthreads();

    const int r  = t >> 3;
    const int c4 = (t & 7) << 2;
    // natural (32 l-rows x 32 m-cols): EN[l][m]=E*p1[l]; S1[l]+=sum_m E*p2[m]
    {
        float4 e = *(const float4*)(affs + r * 36 + c4);
        const float p1r = p1g[(b << 9) + l0 + r];
        float4 vn = make_float4(e.x * p1r, e.y * p1r, e.z * p1r, e.w * p1r);
        *(float4*)(EN + (((b << 9) + l0 + r) << 9) + m0 + c4) = vn;
        float4 p2v = *(const float4*)(p2g + (b << 9) + m0 + c4);
        float s = (e.x * p2v.x + e.y * p2v.y) + (e.z * p2v.z + e.w * p2v.w);
        s += __shfl_xor(s, 1, 64);
        s += __shfl_xor(s, 2, 64);
        s += __shfl_xor(s, 4, 64);
        if ((t & 7) == 0) atomicAdd(S1 + (b << 9) + l0 + r, s);
    }
    // transposed (32 m-rows x 32 l-cols): ET[m][l]=E^T*p2[m]; S2[m]+=sum_l E*p1[l]
    {
        float4 te;
        te.x = affs[(c4 + 0) * 36 + r];
        te.y = affs[(c4 + 1) * 36 + r];
        te.z = affs[(c4 + 2) * 36 + r];
        te.w = affs[(c4 + 3) * 36 + r];
        const float p2r = p2g[(b << 9) + m0 + r];
        float4 vt = make_float4(te.x * p2r, te.y * p2r, te.z * p2r, te.w * p2r);
        *(float4*)(ET + (((b << 9) + m0 + r) << 9) + l0 + c4) = vt;
        float4 p1v = *(const float4*)(p1g + (b << 9) + l0 + c4);
        float s = (te.x * p1v.x + te.y * p1v.y) + (te.z * p1v.z + te.w * p1v.w);
        s += __shfl_xor(s, 1, 64);
        s += __shfl_xor(s, 2, 64);
        s += __shfl_xor(s, 4, 64);
        if ((t & 7) == 0) atomicAdd(S2 + (b << 9) + m0 + r, s);
    }
}

// --------------------------------------------------------------- k_final
__global__ __launch_bounds__(256) void k_final(
    const float* __restrict__ EN, const float* __restrict__ ET,
    const float* __restrict__ U1, const float* __restrict__ U2,
    const float* __restrict__ P12, const float* __restrict__ P21,
    const float* __restrict__ S1, const float* __restrict__ S2,
    float* __restrict__ out)
{
    const int t   = threadIdx.x;
    const int r0  = blockIdx.x * 32, n0 = blockIdx.y * 32;
    const int dir = blockIdx.z >> 1, b = blockIdx.z & 1;
    const float* Ag = (dir == 0 ? ET  : EN)  + b * 262144;  // [row][k], stride 512
    const float* Sg = (dir == 0 ? S1  : S2)  + b * 512;
    const float* Bg = (dir == 0 ? U1  : U2)  + b * 131072;  // [k][n], stride 256
    const float* Pg = (dir == 0 ? P12 : P21) + b * 131072;  // [row][n], stride 256
    float* o = out + (dir == 0 ? 262144 : 0);

    __shared__ __align__(16) short Abf[32 * 72];    // [row][k] bf16, rs folded
    __shared__ __align__(16) short Bbf[32 * 72];    // [n][k] bf16 (U^T)
    __shared__ __align__(16) float rs[512];

    for (int i = t; i < 512; i += 256)
        rs[i] = __builtin_amdgcn_rcpf(Sg[i]);
    __syncthreads();

    const int w    = t >> 6;
    const int lane = t & 63;
    const int quad = lane >> 4;
    const int lr   = lane & 15;
    const int wr   = (w >> 1) << 4, wc = (w & 1) << 4;
    f32x4 acc = {};

    for (int kc = 0; kc < 512; kc += 64) {
        #pragma unroll
        for (int i = 0; i < 2; ++i) {               // A: 32 rows x 64 k, rs-scaled
            int slot = i * 256 + t;
            int r = slot >> 4, kq = (slot & 15) << 2;
            float4 v = *(const float4*)(Ag + ((r0 + r) << 9) + kc + kq);
            const float* rp = rs + kc + kq;
            short4 s;
            s.x = f2bf(v.x * rp[0]); s.y = f2bf(v.y * rp[1]);
            s.z = f2bf(v.z * rp[2]); s.w = f2bf(v.w * rp[3]);
            *(short4*)(Abf + r * 72 + kq) = s;
        }
        #pragma unroll
        for (int i = 0; i < 2; ++i) {               // B: 64 k x 32 n -> [n][k]
            int slot = i * 256 + t;
            int bk = slot >> 3, bn4 = (slot & 7) << 2;
            float4 v = *(const float4*)(Bg + ((kc + bk) << 8) + n0 + bn4);
            Bbf[(bn4 + 0) * 72 + bk] = f2bf(v.x);
            Bbf[(bn4 + 1) * 72 + bk] = f2bf(v.y);
            Bbf[(bn4 + 2) * 72 + bk] = f2bf(v.z);
            Bbf[(bn4 + 3) * 72 + bk] = f2bf(v.w);
        }
        __syncthreads();
        #pragma unroll
        for (int s = 0; s < 2; ++s) {
            const int kb = s * 32 + quad * 8;
            bf16x8 a = *(const bf16x8*)(Abf + (wr + lr) * 72 + kb);
            bf16x8 bb = *(const bf16x8*)(Bbf + (wc + lr) * 72 + kb);
            acc = __builtin_amdgcn_mfma_f32_16x16x32_bf16(a, bb, acc, 0, 0, 0);
        }
        __syncthreads();
    }

    const int col = n0 + wc + lr;
    #pragma unroll
    for (int reg = 0; reg < 4; ++reg) {
        const int m = r0 + wr + quad * 4 + reg;
        float v = acc[reg] + Pg[(m << 8) + col];
        float tv = 1.f - 2.f * __builtin_amdgcn_rcpf(
                       __builtin_amdgcn_exp2f(v * TWO_LOG2E) + 1.f);
        o[((m << 1) + b) * 256 + col] = tv;
    }
}

// ---------------------------------------------------------------- launch
extern "C" void kernel_launch(void* const* d_in, const int* in_sizes, int n_in,
                              void* d_out, int out_size, void* d_ws, size_t ws_size,
                              hipStream_t stream)
{
    const float* ctx1 = (const float*)d_in[0];
    const float* ctx2 = (const float*)d_in[1];
    const float* m1   = (const float*)d_in[2];
    const float* m2   = (const float*)d_in[3];
    const float* Wh   = (const float*)d_in[4];
    const float* bh   = (const float*)d_in[5];
    const float* wo   = (const float*)d_in[6];
    const float* W12  = (const float*)d_in[7];
    const float* b12  = (const float*)d_in[8];
    const float* W21  = (const float*)d_in[9];
    const float* b21  = (const float*)d_in[10];
    float* out = (float*)d_out;
    float* ws  = (float*)d_ws;

    float* E1  = ws;                 // 262144
    float* E2  = E1  + 262144;
    float* P12 = E2  + 262144;
    float* U1  = P12 + 262144;
    float* P21 = U1  + 262144;
    float* U2  = P21 + 262144;
    float* p1  = U2  + 262144;       // 1024
    float* p2  = p1  + 1024;
    float* S1  = p2  + 1024;         // 1024
    float* S2  = S1  + 1024;
    float* EN  = S2  + 1024;         // 524288
    float* ET  = EN  + 524288;       // 524288

    hipLaunchKernelGGL(k_proj, dim3(16, 4, 6), dim3(256), 0, stream,
                       ctx1, ctx2, Wh, bh, W12, b12, W21, b21, m1, m2,
                       E1, E2, P12, U1, P21, U2, p1, p2, S1, S2);
    hipLaunchKernelGGL(k_aff, dim3(16, 16, 2), dim3(256), 0, stream,
                       E1, E2, wo, p1, p2, EN, ET, S1, S2);
    hipLaunchKernelGGL(k_final, dim3(16, 8, 4), dim3(256), 0, stream,
                       EN, ET, U1, U2, P12, P21, S1, S2, out);
}